// Round 1
// baseline (1866.752 us; speedup 1.0000x reference)
//
#include <hip/hip_runtime.h>

typedef unsigned short u16;
typedef unsigned int   u32;
typedef __attribute__((ext_vector_type(8))) short short8; // 8 x bf16 (4 VGPRs)
typedef __attribute__((ext_vector_type(4))) float f32x4;  // mfma accumulator

#define TSEQ   4096
#define DMODEL 512
#define NHEAD  8
#define HDIM   64
#define NLAYER 6
#define MLPD   2048

__device__ __forceinline__ u16 f2b(float f) {
  u32 u = __float_as_uint(f);
  u32 r = (u + 0x7fffu + ((u >> 16) & 1u)) >> 16; // RNE
  return (u16)r;
}
__device__ __forceinline__ float b2f(u16 h) { return __uint_as_float(((u32)h) << 16); }
__device__ __forceinline__ float bflo(u32 u) { return __uint_as_float(u << 16); }
__device__ __forceinline__ float bfhi(u32 u) { return __uint_as_float(u & 0xffff0000u); }

__device__ __forceinline__ void unp8(uint4 u, float* d) {
  d[0] = bflo(u.x); d[1] = bfhi(u.x);
  d[2] = bflo(u.y); d[3] = bfhi(u.y);
  d[4] = bflo(u.z); d[5] = bfhi(u.z);
  d[6] = bflo(u.w); d[7] = bfhi(u.w);
}

// ---------------- weight transpose + fp32->bf16 convert -------------------
// W: [L][K][N] fp32 (layer = blockIdx.z) -> out: [L][Ntot][K] bf16 rows at row-offset ro
__global__ __launch_bounds__(256) void transpose_convert(
    const float* __restrict__ W, u16* __restrict__ out,
    int K, int N, int Ntot, int ro) {
  __shared__ float tile[64][65];
  int l  = blockIdx.z;
  int k0 = blockIdx.x * 64, n0 = blockIdx.y * 64;
  const float* Wl = W + (size_t)l * K * N;
  u16* Ol = out + (size_t)l * Ntot * K;
  int tx = threadIdx.x & 15, ty = threadIdx.x >> 4;
#pragma unroll
  for (int p = 0; p < 4; ++p) {
    int k = k0 + p * 16 + ty;
    float4 v = *(const float4*)(Wl + (size_t)k * N + n0 + tx * 4);
    tile[p * 16 + ty][tx * 4 + 0] = v.x;
    tile[p * 16 + ty][tx * 4 + 1] = v.y;
    tile[p * 16 + ty][tx * 4 + 2] = v.z;
    tile[p * 16 + ty][tx * 4 + 3] = v.w;
  }
  __syncthreads();
#pragma unroll
  for (int p = 0; p < 4; ++p) {
    int n = n0 + p * 16 + ty;
    ushort4 s;
    s.x = f2b(tile[tx * 4 + 0][p * 16 + ty]);
    s.y = f2b(tile[tx * 4 + 1][p * 16 + ty]);
    s.z = f2b(tile[tx * 4 + 2][p * 16 + ty]);
    s.w = f2b(tile[tx * 4 + 3][p * 16 + ty]);
    *(ushort4*)(Ol + (size_t)(ro + n) * K + k0 + tx * 4) = s;
  }
}

// ---------------- embedding + sinusoidal PE -------------------------------
__global__ void embed_pe_kernel(const int* __restrict__ idx,
                                const float* __restrict__ embed,
                                float* __restrict__ x) {
  int i = blockIdx.x;            // 0..B*T-1
  int t = i & (TSEQ - 1);
  int tok = idx[i];
  int c = threadIdx.x * 4;       // 128 threads * 4 = 512
  float4 e = *(const float4*)(embed + (size_t)tok * DMODEL + c);
  float vals[4] = {e.x, e.y, e.z, e.w};
  float o[4];
#pragma unroll
  for (int j = 0; j < 4; ++j) {
    int col = c + j;
    int jj = (col < 256) ? col : col - 256;
    // div[j] = exp(-(2j) * ln(10000)/512)
    float div = expf((float)jj * -0.035977892078032f);
    float arg = (float)t * div;
    o[j] = vals[j] + ((col < 256) ? sinf(arg) : cosf(arg));
  }
  float4 r = {o[0], o[1], o[2], o[3]};
  *(float4*)(x + (size_t)i * DMODEL + c) = r;
}

// ---------------- LayerNorm (wave per row, 2-pass) ------------------------
template <bool OUT_BF16>
__global__ __launch_bounds__(256) void ln_kernel(
    const float* __restrict__ x, const float* __restrict__ gamma,
    const float* __restrict__ beta, void* __restrict__ out) {
  int wave = threadIdx.x >> 6, lane = threadIdx.x & 63;
  int row = (blockIdx.x << 2) + wave;
  const float* xr = x + (size_t)row * DMODEL + lane * 8;
  float4 a = *(const float4*)xr;
  float4 b = *(const float4*)(xr + 4);
  float v[8] = {a.x, a.y, a.z, a.w, b.x, b.y, b.z, b.w};
  float s = 0.f;
#pragma unroll
  for (int j = 0; j < 8; ++j) s += v[j];
#pragma unroll
  for (int off = 1; off < 64; off <<= 1) s += __shfl_xor(s, off, 64);
  float mean = s * (1.0f / 512.0f);
  float q = 0.f;
#pragma unroll
  for (int j = 0; j < 8; ++j) { float d = v[j] - mean; q += d * d; }
#pragma unroll
  for (int off = 1; off < 64; off <<= 1) q += __shfl_xor(q, off, 64);
  float rstd = rsqrtf(q * (1.0f / 512.0f) + 1e-6f);
  float4 g0 = *(const float4*)(gamma + lane * 8);
  float4 g1 = *(const float4*)(gamma + lane * 8 + 4);
  float4 p0 = *(const float4*)(beta + lane * 8);
  float4 p1 = *(const float4*)(beta + lane * 8 + 4);
  float g[8] = {g0.x, g0.y, g0.z, g0.w, g1.x, g1.y, g1.z, g1.w};
  float be[8] = {p0.x, p0.y, p0.z, p0.w, p1.x, p1.y, p1.z, p1.w};
  float r[8];
#pragma unroll
  for (int j = 0; j < 8; ++j) r[j] = (v[j] - mean) * rstd * g[j] + be[j];
  if (OUT_BF16) {
    uint4 pk;
    pk.x = (u32)f2b(r[0]) | ((u32)f2b(r[1]) << 16);
    pk.y = (u32)f2b(r[2]) | ((u32)f2b(r[3]) << 16);
    pk.z = (u32)f2b(r[4]) | ((u32)f2b(r[5]) << 16);
    pk.w = (u32)f2b(r[6]) | ((u32)f2b(r[7]) << 16);
    *(uint4*)((u16*)out + (size_t)row * DMODEL + lane * 8) = pk;
  } else {
    float4 r0 = {r[0], r[1], r[2], r[3]};
    float4 r1 = {r[4], r[5], r[6], r[7]};
    float* op = (float*)out + (size_t)row * DMODEL + lane * 8;
    *(float4*)op = r0;
    *(float4*)(op + 4) = r1;
  }
}

// ---------------- bf16 MFMA GEMM: C[M][N] = A[M][K] * Bt[N][K]^T ----------
// FLAGS: 1=bias, 2=relu, 4=fp32 residual add, 8=bf16 output (else fp32)
template <int FLAGS>
__global__ __launch_bounds__(256) void gemm_kernel(
    const u16* __restrict__ A, const u16* __restrict__ Bt,
    const float* __restrict__ bias, const float* __restrict__ resid,
    void* __restrict__ out, int M, int N, int K) {
  __shared__ __align__(16) u16 a_lds[128][40]; // pad 32->40 shorts (80B stride)
  __shared__ __align__(16) u16 b_lds[128][40];
  int m0 = blockIdx.y * 128, n0 = blockIdx.x * 128;
  int t = threadIdx.x;
  int lr = t >> 2, lc = (t & 3) * 8;
  int wave = t >> 6, lane = t & 63;
  int wm = (wave >> 1) * 64, wn = (wave & 1) * 64;
  int fr = lane & 15, quad = lane >> 4;

  f32x4 acc[4][4];
  f32x4 zz = {0.f, 0.f, 0.f, 0.f};
#pragma unroll
  for (int i = 0; i < 4; ++i)
#pragma unroll
    for (int j = 0; j < 4; ++j) acc[i][j] = zz;

  const u16* Ar0 = A + (size_t)(m0 + lr) * K + lc;
  const u16* Ar1 = A + (size_t)(m0 + lr + 64) * K + lc;
  const u16* Br0 = Bt + (size_t)(n0 + lr) * K + lc;
  const u16* Br1 = Bt + (size_t)(n0 + lr + 64) * K + lc;

  for (int k0 = 0; k0 < K; k0 += 32) {
    uint4 a0 = *(const uint4*)(Ar0 + k0);
    uint4 a1 = *(const uint4*)(Ar1 + k0);
    uint4 b0 = *(const uint4*)(Br0 + k0);
    uint4 b1 = *(const uint4*)(Br1 + k0);
    __syncthreads();
    *(uint4*)&a_lds[lr][lc]      = a0;
    *(uint4*)&a_lds[lr + 64][lc] = a1;
    *(uint4*)&b_lds[lr][lc]      = b0;
    *(uint4*)&b_lds[lr + 64][lc] = b1;
    __syncthreads();
    short8 af[4], bf[4];
#pragma unroll
    for (int mi = 0; mi < 4; ++mi)
      af[mi] = *(const short8*)&a_lds[wm + mi * 16 + fr][quad * 8];
#pragma unroll
    for (int ni = 0; ni < 4; ++ni)
      bf[ni] = *(const short8*)&b_lds[wn + ni * 16 + fr][quad * 8];
#pragma unroll
    for (int mi = 0; mi < 4; ++mi)
#pragma unroll
      for (int ni = 0; ni < 4; ++ni)
        acc[mi][ni] = __builtin_amdgcn_mfma_f32_16x16x32_bf16(
            af[mi], bf[ni], acc[mi][ni], 0, 0, 0);
  }

#pragma unroll
  for (int mi = 0; mi < 4; ++mi)
#pragma unroll
    for (int ni = 0; ni < 4; ++ni) {
      int colg = n0 + wn + ni * 16 + fr;
      float bv = (FLAGS & 1) ? bias[colg] : 0.0f;
#pragma unroll
      for (int r = 0; r < 4; ++r) {
        int rowg = m0 + wm + mi * 16 + quad * 4 + r;
        float val = acc[mi][ni][r] + bv;
        if (FLAGS & 2) val = fmaxf(val, 0.0f);
        if (FLAGS & 4) val += resid[(size_t)rowg * N + colg];
        if (FLAGS & 8)
          ((u16*)out)[(size_t)rowg * N + colg] = f2b(val);
        else
          ((float*)out)[(size_t)rowg * N + colg] = val;
      }
    }
}

// ---------------- local block attention -----------------------------------
// qkv: [B*T][1536] bf16 (q|k|v, each [H][64]); o: [B*T][512] bf16
// one workgroup per (block n, head h, batch b); sh = 32 for staggered layers
__global__ __launch_bounds__(256) void attn_kernel(
    const u16* __restrict__ qkv, const int* __restrict__ tokens,
    u16* __restrict__ o, int sh) {
  __shared__ __align__(16) float qs[64][68];
  __shared__ __align__(16) float ks[64][68];
  __shared__ __align__(16) u16 vs[64][64];
  __shared__ __align__(16) float ss[64][65];
  __shared__ float kmask[64];
  int n = blockIdx.x, h = blockIdx.y, b = blockIdx.z;
  int tid = threadIdx.x;
  {
    int srow = tid >> 2;
    int cg = (tid & 3) << 4;             // 16 cols per thread
    int p = n * 64 + srow - sh;
    if (tid < 64) {
      int pp = n * 64 + tid - sh;
      kmask[tid] =
          (pp >= 0 && pp < TSEQ && tokens[(size_t)b * TSEQ + pp] > 0) ? 1.0f : 0.0f;
    }
    if (p >= 0 && p < TSEQ) {
      const u16* base = qkv + ((size_t)(b * TSEQ + p)) * 1536 + h * HDIM + cg;
      uint4 qa = *(const uint4*)(base);
      uint4 qb = *(const uint4*)(base + 8);
      uint4 ka = *(const uint4*)(base + 512);
      uint4 kb = *(const uint4*)(base + 520);
      uint4 va = *(const uint4*)(base + 1024);
      uint4 vb = *(const uint4*)(base + 1032);
      unp8(qa, &qs[srow][cg]);
      unp8(qb, &qs[srow][cg + 8]);
      unp8(ka, &ks[srow][cg]);
      unp8(kb, &ks[srow][cg + 8]);
      *(uint4*)&vs[srow][cg] = va;
      *(uint4*)&vs[srow][cg + 8] = vb;
    } else {
      float4 z4 = {0.f, 0.f, 0.f, 0.f};
      uint4 z = {0u, 0u, 0u, 0u};
#pragma unroll
      for (int j = 0; j < 4; ++j) {
        *(float4*)&qs[srow][cg + 4 * j] = z4;
        *(float4*)&ks[srow][cg + 4 * j] = z4;
      }
      *(uint4*)&vs[srow][cg] = z;
      *(uint4*)&vs[srow][cg + 8] = z;
    }
  }
  __syncthreads();
  int i0 = (tid >> 4) << 2;   // 4 query rows
  int c0 = (tid & 15) << 2;   // 4 key cols (then 4 output f cols)
  float a4[4][4];
#pragma unroll
  for (int a = 0; a < 4; ++a)
#pragma unroll
    for (int c = 0; c < 4; ++c) a4[a][c] = 0.f;
  for (int f = 0; f < 64; f += 4) {
    float4 qv[4], kv[4];
#pragma unroll
    for (int a = 0; a < 4; ++a) qv[a] = *(const float4*)&qs[i0 + a][f];
#pragma unroll
    for (int c = 0; c < 4; ++c) kv[c] = *(const float4*)&ks[c0 + c][f];
#pragma unroll
    for (int a = 0; a < 4; ++a)
#pragma unroll
      for (int c = 0; c < 4; ++c)
        a4[a][c] += qv[a].x * kv[c].x + qv[a].y * kv[c].y +
                    qv[a].z * kv[c].z + qv[a].w * kv[c].w;
  }
#pragma unroll
  for (int a = 0; a < 4; ++a)
#pragma unroll
    for (int c = 0; c < 4; ++c)
      ss[i0 + a][c0 + c] =
          (kmask[c0 + c] > 0.f) ? 0.125f * a4[a][c] : -1.0e9f;
  __syncthreads();
  if (tid < 64) {
    float m = -3.0e38f;
#pragma unroll
    for (int j = 0; j < 64; ++j) m = fmaxf(m, ss[tid][j]);
    float sum = 0.f;
#pragma unroll
    for (int j = 0; j < 64; ++j) {
      float e = __expf(ss[tid][j] - m);
      ss[tid][j] = e;
      sum += e;
    }
    float inv = 1.0f / sum;
#pragma unroll
    for (int j = 0; j < 64; ++j) ss[tid][j] *= inv;
  }
  __syncthreads();
  float o4[4][4];
#pragma unroll
  for (int a = 0; a < 4; ++a)
#pragma unroll
    for (int c = 0; c < 4; ++c) o4[a][c] = 0.f;
  for (int j = 0; j < 64; ++j) {
    float pv[4];
#pragma unroll
    for (int a = 0; a < 4; ++a) pv[a] = ss[i0 + a][j];
    ushort4 vraw = *(const ushort4*)&vs[j][c0];
    float v0 = b2f(vraw.x), v1 = b2f(vraw.y), v2 = b2f(vraw.z), v3 = b2f(vraw.w);
#pragma unroll
    for (int a = 0; a < 4; ++a) {
      o4[a][0] += pv[a] * v0;
      o4[a][1] += pv[a] * v1;
      o4[a][2] += pv[a] * v2;
      o4[a][3] += pv[a] * v3;
    }
  }
#pragma unroll
  for (int a = 0; a < 4; ++a) {
    int pq = n * 64 + i0 + a - sh;
    if (pq >= 0 && pq < TSEQ) {
      ushort4 st;
      st.x = f2b(o4[a][0]);
      st.y = f2b(o4[a][1]);
      st.z = f2b(o4[a][2]);
      st.w = f2b(o4[a][3]);
      *(ushort4*)(o + ((size_t)(b * TSEQ + pq)) * DMODEL + h * HDIM + c0) = st;
    }
  }
}

// ---------------------------------------------------------------------------
extern "C" void kernel_launch(void* const* d_in, const int* in_sizes, int n_in,
                              void* d_out, int out_size, void* d_ws, size_t ws_size,
                              hipStream_t stream) {
  (void)in_sizes; (void)n_in; (void)out_size; (void)ws_size;
  const int*   tokens = (const int*)d_in[0];
  const float* embed  = (const float*)d_in[1];
  const float* wq = (const float*)d_in[2];
  const float* wk = (const float*)d_in[3];
  const float* wv = (const float*)d_in[4];
  const float* wo = (const float*)d_in[5];
  const float* ln1_s = (const float*)d_in[6];
  const float* ln1_b = (const float*)d_in[7];
  const float* ln2_s = (const float*)d_in[8];
  const float* ln2_b = (const float*)d_in[9];
  const float* w1 = (const float*)d_in[10];
  const float* b1 = (const float*)d_in[11];
  const float* w2 = (const float*)d_in[12];
  const float* b2 = (const float*)d_in[13];
  const float* lnf_s = (const float*)d_in[14];
  const float* lnf_b = (const float*)d_in[15];

  char* ws = (char*)d_ws;
  const size_t MB = 1024ull * 1024ull;
  float* x     = (float*)(ws + 0);        // 32 MB fp32 residual stream
  u16* h       = (u16*)(ws + 32 * MB);    // 16 MB bf16 LN output
  u16* qkv     = (u16*)(ws + 48 * MB);    // 48 MB bf16
  u16* obuf    = (u16*)(ws + 96 * MB);    // 16 MB bf16
  u16* hidden  = (u16*)(ws + 48 * MB);    // 64 MB bf16 (aliases qkv+obuf, disjoint in time)
  u16* wqkv_bt = (u16*)(ws + 112 * MB);   // 9 MB
  u16* wo_bt   = (u16*)(ws + 121 * MB);   // 3 MB
  u16* w1_bt   = (u16*)(ws + 124 * MB);   // 12 MB
  u16* w2_bt   = (u16*)(ws + 136 * MB);   // 12 MB  (total 148 MB)

  // weight convert+transpose to bf16 [N][K]
  transpose_convert<<<dim3(8, 8, 6), 256, 0, stream>>>(wq, wqkv_bt, 512, 512, 1536, 0);
  transpose_convert<<<dim3(8, 8, 6), 256, 0, stream>>>(wk, wqkv_bt, 512, 512, 1536, 512);
  transpose_convert<<<dim3(8, 8, 6), 256, 0, stream>>>(wv, wqkv_bt, 512, 512, 1536, 1024);
  transpose_convert<<<dim3(8, 8, 6), 256, 0, stream>>>(wo, wo_bt, 512, 512, 512, 0);
  transpose_convert<<<dim3(8, 32, 6), 256, 0, stream>>>(w1, w1_bt, 512, 2048, 2048, 0);
  transpose_convert<<<dim3(32, 8, 6), 256, 0, stream>>>(w2, w2_bt, 2048, 512, 512, 0);

  embed_pe_kernel<<<16384, 128, 0, stream>>>(tokens, embed, x);

  for (int l = 0; l < NLAYER; ++l) {
    int sh = (l & 1) ? 32 : 0;
    int nb = (l & 1) ? 65 : 64;
    ln_kernel<true><<<4096, 256, 0, stream>>>(x, ln1_s + l * 512, ln1_b + l * 512, h);
    gemm_kernel<8><<<dim3(12, 128), 256, 0, stream>>>(
        h, wqkv_bt + (size_t)l * 1536 * 512, nullptr, nullptr, qkv, 16384, 1536, 512);
    attn_kernel<<<dim3(nb, NHEAD, 4), 256, 0, stream>>>(qkv, tokens, obuf, sh);
    gemm_kernel<4><<<dim3(4, 128), 256, 0, stream>>>(
        obuf, wo_bt + (size_t)l * 512 * 512, nullptr, x, x, 16384, 512, 512);
    ln_kernel<true><<<4096, 256, 0, stream>>>(x, ln2_s + l * 512, ln2_b + l * 512, h);
    gemm_kernel<1 | 2 | 8><<<dim3(16, 128), 256, 0, stream>>>(
        h, w1_bt + (size_t)l * 2048 * 512, b1 + l * 2048, nullptr, hidden, 16384, 2048, 512);
    gemm_kernel<1 | 4><<<dim3(4, 128), 256, 0, stream>>>(
        hidden, w2_bt + (size_t)l * 512 * 2048, b2 + l * 512, x, x, 16384, 512, 2048);
  }
  ln_kernel<false><<<4096, 256, 0, stream>>>(x, lnf_s, lnf_b, d_out);
}

// Round 2
// 1825.610 us; speedup vs baseline: 1.0225x; 1.0225x over previous
//
#include <hip/hip_runtime.h>

typedef unsigned short u16;
typedef unsigned int   u32;
typedef __attribute__((ext_vector_type(8))) short short8; // 8 x bf16 (4 VGPRs)
typedef __attribute__((ext_vector_type(4))) float f32x4;  // mfma accumulator

#define TSEQ   4096
#define DMODEL 512
#define NHEAD  8
#define HDIM   64
#define NLAYER 6
#define MLPD   2048

#define GPTR(p) (const __attribute__((address_space(1))) void*)(p)
#define LPTR(p) (__attribute__((address_space(3))) void*)(p)

__device__ __forceinline__ u16 f2b(float f) {
  u32 u = __float_as_uint(f);
  u32 r = (u + 0x7fffu + ((u >> 16) & 1u)) >> 16; // RNE
  return (u16)r;
}
__device__ __forceinline__ float b2f(u16 h) { return __uint_as_float(((u32)h) << 16); }
__device__ __forceinline__ float bflo(u32 u) { return __uint_as_float(u << 16); }
__device__ __forceinline__ float bfhi(u32 u) { return __uint_as_float(u & 0xffff0000u); }

__device__ __forceinline__ void unp8(uint4 u, float* d) {
  d[0] = bflo(u.x); d[1] = bfhi(u.x);
  d[2] = bflo(u.y); d[3] = bfhi(u.y);
  d[4] = bflo(u.z); d[5] = bfhi(u.z);
  d[6] = bflo(u.w); d[7] = bfhi(u.w);
}

// ---------------- weight transpose + fp32->bf16 convert -------------------
// W: [L][K][N] fp32 (layer = blockIdx.z) -> out: [L][Ntot][K] bf16 rows at row-offset ro
__global__ __launch_bounds__(256) void transpose_convert(
    const float* __restrict__ W, u16* __restrict__ out,
    int K, int N, int Ntot, int ro) {
  __shared__ float tile[64][65];
  int l  = blockIdx.z;
  int k0 = blockIdx.x * 64, n0 = blockIdx.y * 64;
  const float* Wl = W + (size_t)l * K * N;
  u16* Ol = out + (size_t)l * Ntot * K;
  int tx = threadIdx.x & 15, ty = threadIdx.x >> 4;
#pragma unroll
  for (int p = 0; p < 4; ++p) {
    int k = k0 + p * 16 + ty;
    float4 v = *(const float4*)(Wl + (size_t)k * N + n0 + tx * 4);
    tile[p * 16 + ty][tx * 4 + 0] = v.x;
    tile[p * 16 + ty][tx * 4 + 1] = v.y;
    tile[p * 16 + ty][tx * 4 + 2] = v.z;
    tile[p * 16 + ty][tx * 4 + 3] = v.w;
  }
  __syncthreads();
#pragma unroll
  for (int p = 0; p < 4; ++p) {
    int n = n0 + p * 16 + ty;
    ushort4 s;
    s.x = f2b(tile[tx * 4 + 0][p * 16 + ty]);
    s.y = f2b(tile[tx * 4 + 1][p * 16 + ty]);
    s.z = f2b(tile[tx * 4 + 2][p * 16 + ty]);
    s.w = f2b(tile[tx * 4 + 3][p * 16 + ty]);
    *(ushort4*)(Ol + (size_t)(ro + n) * K + k0 + tx * 4) = s;
  }
}

// ---------------- embedding + sinusoidal PE -------------------------------
__global__ void embed_pe_kernel(const int* __restrict__ idx,
                                const float* __restrict__ embed,
                                float* __restrict__ x) {
  int i = blockIdx.x;            // 0..B*T-1
  int t = i & (TSEQ - 1);
  int tok = idx[i];
  int c = threadIdx.x * 4;       // 128 threads * 4 = 512
  float4 e = *(const float4*)(embed + (size_t)tok * DMODEL + c);
  float vals[4] = {e.x, e.y, e.z, e.w};
  float o[4];
#pragma unroll
  for (int j = 0; j < 4; ++j) {
    int col = c + j;
    int jj = (col < 256) ? col : col - 256;
    // div[j] = exp(-(2j) * ln(10000)/512)
    float div = __expf((float)jj * -0.035977892078032f);
    float arg = (float)t * div;
    o[j] = vals[j] + ((col < 256) ? __sinf(arg) : __cosf(arg));
  }
  float4 r = {o[0], o[1], o[2], o[3]};
  *(float4*)(x + (size_t)i * DMODEL + c) = r;
}

// ---------------- LayerNorm (wave per row, 2-pass) ------------------------
template <bool OUT_BF16>
__global__ __launch_bounds__(256) void ln_kernel(
    const float* __restrict__ x, const float* __restrict__ gamma,
    const float* __restrict__ beta, void* __restrict__ out) {
  int wave = threadIdx.x >> 6, lane = threadIdx.x & 63;
  int row = (blockIdx.x << 2) + wave;
  const float* xr = x + (size_t)row * DMODEL + lane * 8;
  float4 a = *(const float4*)xr;
  float4 b = *(const float4*)(xr + 4);
  float v[8] = {a.x, a.y, a.z, a.w, b.x, b.y, b.z, b.w};
  float s = 0.f;
#pragma unroll
  for (int j = 0; j < 8; ++j) s += v[j];
#pragma unroll
  for (int off = 1; off < 64; off <<= 1) s += __shfl_xor(s, off, 64);
  float mean = s * (1.0f / 512.0f);
  float q = 0.f;
#pragma unroll
  for (int j = 0; j < 8; ++j) { float d = v[j] - mean; q += d * d; }
#pragma unroll
  for (int off = 1; off < 64; off <<= 1) q += __shfl_xor(q, off, 64);
  float rstd = rsqrtf(q * (1.0f / 512.0f) + 1e-6f);
  float4 g0 = *(const float4*)(gamma + lane * 8);
  float4 g1 = *(const float4*)(gamma + lane * 8 + 4);
  float4 p0 = *(const float4*)(beta + lane * 8);
  float4 p1 = *(const float4*)(beta + lane * 8 + 4);
  float g[8] = {g0.x, g0.y, g0.z, g0.w, g1.x, g1.y, g1.z, g1.w};
  float be[8] = {p0.x, p0.y, p0.z, p0.w, p1.x, p1.y, p1.z, p1.w};
  float r[8];
#pragma unroll
  for (int j = 0; j < 8; ++j) r[j] = (v[j] - mean) * rstd * g[j] + be[j];
  if (OUT_BF16) {
    uint4 pk;
    pk.x = (u32)f2b(r[0]) | ((u32)f2b(r[1]) << 16);
    pk.y = (u32)f2b(r[2]) | ((u32)f2b(r[3]) << 16);
    pk.z = (u32)f2b(r[4]) | ((u32)f2b(r[5]) << 16);
    pk.w = (u32)f2b(r[6]) | ((u32)f2b(r[7]) << 16);
    *(uint4*)((u16*)out + (size_t)row * DMODEL + lane * 8) = pk;
  } else {
    float4 r0 = {r[0], r[1], r[2], r[3]};
    float4 r1 = {r[4], r[5], r[6], r[7]};
    float* op = (float*)out + (size_t)row * DMODEL + lane * 8;
    *(float4*)op = r0;
    *(float4*)(op + 4) = r1;
  }
}

// ---------------- bf16 MFMA GEMM: C[M][N] = A[M][K] * Bt[N][K]^T ----------
// m97 structure: global_load_lds width-16 staging (LDS layout contiguous in
// thread order — NO padding allowed), ds_read_b128 fragments, 4x4 mfma/wave.
// FLAGS: 1=bias, 2=relu, 4=fp32 residual add, 8=bf16 output (else fp32)
template <int FLAGS>
__global__ __launch_bounds__(256) void gemm_kernel(
    const u16* __restrict__ A, const u16* __restrict__ Bt,
    const float* __restrict__ bias, const float* __restrict__ resid,
    void* __restrict__ out, int M, int N, int K) {
  __shared__ __align__(16) u16 a_lds[128][32]; // flat offset = tid*16B per half
  __shared__ __align__(16) u16 b_lds[128][32];
  int m0 = blockIdx.y * 128, n0 = blockIdx.x * 128;
  int t = threadIdx.x;
  int lr = t >> 2, lc = (t & 3) * 8;
  int wave = t >> 6, lane = t & 63;
  int wm = (wave >> 1) * 64, wn = (wave & 1) * 64;
  int fr = lane & 15, quad = lane >> 4;

  f32x4 acc[4][4];
  f32x4 zz = {0.f, 0.f, 0.f, 0.f};
#pragma unroll
  for (int i = 0; i < 4; ++i)
#pragma unroll
    for (int j = 0; j < 4; ++j) acc[i][j] = zz;

  const u16* Ag0 = A + (size_t)(m0 + lr) * K + lc;
  const u16* Ag1 = A + (size_t)(m0 + lr + 64) * K + lc;
  const u16* Bg0 = Bt + (size_t)(n0 + lr) * K + lc;
  const u16* Bg1 = Bt + (size_t)(n0 + lr + 64) * K + lc;
  u16* lA0 = &a_lds[lr][lc];
  u16* lA1 = &a_lds[lr + 64][lc];
  u16* lB0 = &b_lds[lr][lc];
  u16* lB1 = &b_lds[lr + 64][lc];

  for (int k0 = 0; k0 < K; k0 += 32) {
    __syncthreads();  // previous iteration's fragment reads complete
    __builtin_amdgcn_global_load_lds(GPTR(Ag0 + k0), LPTR(lA0), 16, 0, 0);
    __builtin_amdgcn_global_load_lds(GPTR(Ag1 + k0), LPTR(lA1), 16, 0, 0);
    __builtin_amdgcn_global_load_lds(GPTR(Bg0 + k0), LPTR(lB0), 16, 0, 0);
    __builtin_amdgcn_global_load_lds(GPTR(Bg1 + k0), LPTR(lB1), 16, 0, 0);
    __syncthreads();  // drains vmcnt: staged data visible
    short8 af[4], bf[4];
#pragma unroll
    for (int mi = 0; mi < 4; ++mi)
      af[mi] = *(const short8*)&a_lds[wm + mi * 16 + fr][quad * 8];
#pragma unroll
    for (int ni = 0; ni < 4; ++ni)
      bf[ni] = *(const short8*)&b_lds[wn + ni * 16 + fr][quad * 8];
#pragma unroll
    for (int mi = 0; mi < 4; ++mi)
#pragma unroll
      for (int ni = 0; ni < 4; ++ni)
        acc[mi][ni] = __builtin_amdgcn_mfma_f32_16x16x32_bf16(
            af[mi], bf[ni], acc[mi][ni], 0, 0, 0);
  }

#pragma unroll
  for (int mi = 0; mi < 4; ++mi)
#pragma unroll
    for (int ni = 0; ni < 4; ++ni) {
      int colg = n0 + wn + ni * 16 + fr;
      float bv = (FLAGS & 1) ? bias[colg] : 0.0f;
#pragma unroll
      for (int r = 0; r < 4; ++r) {
        int rowg = m0 + wm + mi * 16 + quad * 4 + r;
        float val = acc[mi][ni][r] + bv;
        if (FLAGS & 2) val = fmaxf(val, 0.0f);
        if (FLAGS & 4) val += resid[(size_t)rowg * N + colg];
        if (FLAGS & 8)
          ((u16*)out)[(size_t)rowg * N + colg] = f2b(val);
        else
          ((float*)out)[(size_t)rowg * N + colg] = val;
      }
    }
}

// ---------------- local block attention -----------------------------------
// qkv: [B*T][1536] bf16 (q|k|v, each [H][64]); o: [B*T][512] bf16
// one workgroup per (block n, head h, batch b); sh = 32 for staggered layers
__global__ __launch_bounds__(256) void attn_kernel(
    const u16* __restrict__ qkv, const int* __restrict__ tokens,
    u16* __restrict__ o, int sh) {
  __shared__ __align__(16) float qs[64][68];
  __shared__ __align__(16) float ks[64][68];
  __shared__ __align__(16) u16 vs[64][64];
  __shared__ __align__(16) float ss[64][65];
  __shared__ float kmask[64];
  int n = blockIdx.x, h = blockIdx.y, b = blockIdx.z;
  int tid = threadIdx.x;
  {
    int srow = tid >> 2;
    int cg = (tid & 3) << 4;             // 16 cols per thread
    int p = n * 64 + srow - sh;
    if (tid < 64) {
      int pp = n * 64 + tid - sh;
      kmask[tid] =
          (pp >= 0 && pp < TSEQ && tokens[(size_t)b * TSEQ + pp] > 0) ? 1.0f : 0.0f;
    }
    if (p >= 0 && p < TSEQ) {
      const u16* base = qkv + ((size_t)(b * TSEQ + p)) * 1536 + h * HDIM + cg;
      uint4 qa = *(const uint4*)(base);
      uint4 qb = *(const uint4*)(base + 8);
      uint4 ka = *(const uint4*)(base + 512);
      uint4 kb = *(const uint4*)(base + 520);
      uint4 va = *(const uint4*)(base + 1024);
      uint4 vb = *(const uint4*)(base + 1032);
      unp8(qa, &qs[srow][cg]);
      unp8(qb, &qs[srow][cg + 8]);
      unp8(ka, &ks[srow][cg]);
      unp8(kb, &ks[srow][cg + 8]);
      *(uint4*)&vs[srow][cg] = va;
      *(uint4*)&vs[srow][cg + 8] = vb;
    } else {
      float4 z4 = {0.f, 0.f, 0.f, 0.f};
      uint4 z = {0u, 0u, 0u, 0u};
#pragma unroll
      for (int j = 0; j < 4; ++j) {
        *(float4*)&qs[srow][cg + 4 * j] = z4;
        *(float4*)&ks[srow][cg + 4 * j] = z4;
      }
      *(uint4*)&vs[srow][cg] = z;
      *(uint4*)&vs[srow][cg + 8] = z;
    }
  }
  __syncthreads();
  int i0 = (tid >> 4) << 2;   // 4 query rows
  int c0 = (tid & 15) << 2;   // 4 key cols (then 4 output f cols)
  float a4[4][4];
#pragma unroll
  for (int a = 0; a < 4; ++a)
#pragma unroll
    for (int c = 0; c < 4; ++c) a4[a][c] = 0.f;
  for (int f = 0; f < 64; f += 4) {
    float4 qv[4], kv[4];
#pragma unroll
    for (int a = 0; a < 4; ++a) qv[a] = *(const float4*)&qs[i0 + a][f];
#pragma unroll
    for (int c = 0; c < 4; ++c) kv[c] = *(const float4*)&ks[c0 + c][f];
#pragma unroll
    for (int a = 0; a < 4; ++a)
#pragma unroll
      for (int c = 0; c < 4; ++c)
        a4[a][c] += qv[a].x * kv[c].x + qv[a].y * kv[c].y +
                    qv[a].z * kv[c].z + qv[a].w * kv[c].w;
  }
#pragma unroll
  for (int a = 0; a < 4; ++a)
#pragma unroll
    for (int c = 0; c < 4; ++c)
      ss[i0 + a][c0 + c] =
          (kmask[c0 + c] > 0.f) ? 0.125f * a4[a][c] : -1.0e9f;
  __syncthreads();
  if (tid < 64) {
    float m = -3.0e38f;
#pragma unroll
    for (int j = 0; j < 64; ++j) m = fmaxf(m, ss[tid][j]);
    float sum = 0.f;
#pragma unroll
    for (int j = 0; j < 64; ++j) {
      float e = __expf(ss[tid][j] - m);
      ss[tid][j] = e;
      sum += e;
    }
    float inv = 1.0f / sum;
#pragma unroll
    for (int j = 0; j < 64; ++j) ss[tid][j] *= inv;
  }
  __syncthreads();
  float o4[4][4];
#pragma unroll
  for (int a = 0; a < 4; ++a)
#pragma unroll
    for (int c = 0; c < 4; ++c) o4[a][c] = 0.f;
  for (int j = 0; j < 64; ++j) {
    float pv[4];
#pragma unroll
    for (int a = 0; a < 4; ++a) pv[a] = ss[i0 + a][j];
    ushort4 vraw = *(const ushort4*)&vs[j][c0];
    float v0 = b2f(vraw.x), v1 = b2f(vraw.y), v2 = b2f(vraw.z), v3 = b2f(vraw.w);
#pragma unroll
    for (int a = 0; a < 4; ++a) {
      o4[a][0] += pv[a] * v0;
      o4[a][1] += pv[a] * v1;
      o4[a][2] += pv[a] * v2;
      o4[a][3] += pv[a] * v3;
    }
  }
#pragma unroll
  for (int a = 0; a < 4; ++a) {
    int pq = n * 64 + i0 + a - sh;
    if (pq >= 0 && pq < TSEQ) {
      ushort4 st;
      st.x = f2b(o4[a][0]);
      st.y = f2b(o4[a][1]);
      st.z = f2b(o4[a][2]);
      st.w = f2b(o4[a][3]);
      *(ushort4*)(o + ((size_t)(b * TSEQ + pq)) * DMODEL + h * HDIM + c0) = st;
    }
  }
}

// ---------------------------------------------------------------------------
extern "C" void kernel_launch(void* const* d_in, const int* in_sizes, int n_in,
                              void* d_out, int out_size, void* d_ws, size_t ws_size,
                              hipStream_t stream) {
  (void)in_sizes; (void)n_in; (void)out_size; (void)ws_size;
  const int*   tokens = (const int*)d_in[0];
  const float* embed  = (const float*)d_in[1];
  const float* wq = (const float*)d_in[2];
  const float* wk = (const float*)d_in[3];
  const float* wv = (const float*)d_in[4];
  const float* wo = (const float*)d_in[5];
  const float* ln1_s = (const float*)d_in[6];
  const float* ln1_b = (const float*)d_in[7];
  const float* ln2_s = (const float*)d_in[8];
  const float* ln2_b = (const float*)d_in[9];
  const float* w1 = (const float*)d_in[10];
  const float* b1 = (const float*)d_in[11];
  const float* w2 = (const float*)d_in[12];
  const float* b2 = (const float*)d_in[13];
  const float* lnf_s = (const float*)d_in[14];
  const float* lnf_b = (const float*)d_in[15];

  char* ws = (char*)d_ws;
  const size_t MB = 1024ull * 1024ull;
  float* x     = (float*)(ws + 0);        // 32 MB fp32 residual stream
  u16* h       = (u16*)(ws + 32 * MB);    // 16 MB bf16 LN output
  u16* qkv     = (u16*)(ws + 48 * MB);    // 48 MB bf16
  u16* obuf    = (u16*)(ws + 96 * MB);    // 16 MB bf16
  u16* hidden  = (u16*)(ws + 48 * MB);    // 64 MB bf16 (aliases qkv+obuf, disjoint in time)
  u16* wqkv_bt = (u16*)(ws + 112 * MB);   // 9 MB
  u16* wo_bt   = (u16*)(ws + 121 * MB);   // 3 MB
  u16* w1_bt   = (u16*)(ws + 124 * MB);   // 12 MB
  u16* w2_bt   = (u16*)(ws + 136 * MB);   // 12 MB  (total 148 MB)

  // weight convert+transpose to bf16 [N][K]
  transpose_convert<<<dim3(8, 8, 6), 256, 0, stream>>>(wq, wqkv_bt, 512, 512, 1536, 0);
  transpose_convert<<<dim3(8, 8, 6), 256, 0, stream>>>(wk, wqkv_bt, 512, 512, 1536, 512);
  transpose_convert<<<dim3(8, 8, 6), 256, 0, stream>>>(wv, wqkv_bt, 512, 512, 1536, 1024);
  transpose_convert<<<dim3(8, 8, 6), 256, 0, stream>>>(wo, wo_bt, 512, 512, 512, 0);
  transpose_convert<<<dim3(8, 32, 6), 256, 0, stream>>>(w1, w1_bt, 512, 2048, 2048, 0);
  transpose_convert<<<dim3(32, 8, 6), 256, 0, stream>>>(w2, w2_bt, 2048, 512, 512, 0);

  embed_pe_kernel<<<16384, 128, 0, stream>>>(tokens, embed, x);

  for (int l = 0; l < NLAYER; ++l) {
    int sh = (l & 1) ? 32 : 0;
    int nb = (l & 1) ? 65 : 64;
    ln_kernel<true><<<4096, 256, 0, stream>>>(x, ln1_s + l * 512, ln1_b + l * 512, h);
    gemm_kernel<8><<<dim3(12, 128), 256, 0, stream>>>(
        h, wqkv_bt + (size_t)l * 1536 * 512, nullptr, nullptr, qkv, 16384, 1536, 512);
    attn_kernel<<<dim3(nb, NHEAD, 4), 256, 0, stream>>>(qkv, tokens, obuf, sh);
    gemm_kernel<4><<<dim3(4, 128), 256, 0, stream>>>(
        obuf, wo_bt + (size_t)l * 512 * 512, nullptr, x, x, 16384, 512, 512);
    ln_kernel<true><<<4096, 256, 0, stream>>>(x, ln2_s + l * 512, ln2_b + l * 512, h);
    gemm_kernel<1 | 2 | 8><<<dim3(16, 128), 256, 0, stream>>>(
        h, w1_bt + (size_t)l * 2048 * 512, b1 + l * 2048, nullptr, hidden, 16384, 2048, 512);
    gemm_kernel<1 | 4><<<dim3(4, 128), 256, 0, stream>>>(
        hidden, w2_bt + (size_t)l * 512 * 2048, b2 + l * 512, x, x, 16384, 512, 2048);
  }
  ln_kernel<false><<<4096, 256, 0, stream>>>(x, lnf_s, lnf_b, d_out);
}

// Round 3
// 1628.136 us; speedup vs baseline: 1.1466x; 1.1213x over previous
//
#include <hip/hip_runtime.h>

typedef unsigned short u16;
typedef unsigned int   u32;
typedef __attribute__((ext_vector_type(8))) short short8; // 8 x bf16 (4 VGPRs)
typedef __attribute__((ext_vector_type(4))) float f32x4;  // mfma accumulator

#define TSEQ   4096
#define DMODEL 512
#define NHEAD  8
#define HDIM   64
#define NLAYER 6
#define MLPD   2048

#define GPTR(p) (const __attribute__((address_space(1))) void*)(p)
#define LPTR(p) (__attribute__((address_space(3))) void*)(p)

__device__ __forceinline__ u16 f2b(float f) {
  u32 u = __float_as_uint(f);
  u32 r = (u + 0x7fffu + ((u >> 16) & 1u)) >> 16; // RNE
  return (u16)r;
}
__device__ __forceinline__ float b2f(u16 h) { return __uint_as_float(((u32)h) << 16); }

__device__ __forceinline__ short8 ld8g(const u16* p, bool ok) {
  if (ok) return *(const short8*)p;
  short8 z = {0, 0, 0, 0, 0, 0, 0, 0};
  return z;
}

// ---------------- merged weight transpose + fp32->bf16 convert ------------
// grid (768, 6): bx<256: wq/wk/wv/wo (8x8 tiles each); 256..511: w1 (8x32);
// 512..767: w2 (32x8). Output layout: [L][Ntot][K] bf16 at row-offset ro.
__global__ __launch_bounds__(256) void transpose_convert_all(
    const float* __restrict__ wq, const float* __restrict__ wk,
    const float* __restrict__ wv, const float* __restrict__ wo,
    const float* __restrict__ w1, const float* __restrict__ w2,
    u16* __restrict__ wqkv_bt, u16* __restrict__ wo_bt,
    u16* __restrict__ w1_bt, u16* __restrict__ w2_bt) {
  __shared__ float tile[64][65];
  int bx = blockIdx.x, l = blockIdx.y;
  const float* W; u16* out; int K, N, Ntot, ro, kb, nb2;
  if (bx < 256) {
    int which = bx >> 6, local = bx & 63;
    K = 512; N = 512; kb = local & 7; nb2 = local >> 3;
    if (which == 0)      { W = wq; out = wqkv_bt; Ntot = 1536; ro = 0; }
    else if (which == 1) { W = wk; out = wqkv_bt; Ntot = 1536; ro = 512; }
    else if (which == 2) { W = wv; out = wqkv_bt; Ntot = 1536; ro = 1024; }
    else                 { W = wo; out = wo_bt;   Ntot = 512;  ro = 0; }
  } else if (bx < 512) {
    int local = bx - 256;
    W = w1; out = w1_bt; K = 512; N = 2048; Ntot = 2048; ro = 0;
    kb = local & 7; nb2 = local >> 3;
  } else {
    int local = bx - 512;
    W = w2; out = w2_bt; K = 2048; N = 512; Ntot = 512; ro = 0;
    kb = local >> 3; nb2 = local & 7;
  }
  int k0 = kb * 64, n0 = nb2 * 64;
  const float* Wl = W + (size_t)l * K * N;
  u16* Ol = out + (size_t)l * Ntot * K;
  int tx = threadIdx.x & 15, ty = threadIdx.x >> 4;
#pragma unroll
  for (int p = 0; p < 4; ++p) {
    int k = k0 + p * 16 + ty;
    float4 v = *(const float4*)(Wl + (size_t)k * N + n0 + tx * 4);
    tile[p * 16 + ty][tx * 4 + 0] = v.x;
    tile[p * 16 + ty][tx * 4 + 1] = v.y;
    tile[p * 16 + ty][tx * 4 + 2] = v.z;
    tile[p * 16 + ty][tx * 4 + 3] = v.w;
  }
  __syncthreads();
#pragma unroll
  for (int p = 0; p < 4; ++p) {
    int n = n0 + p * 16 + ty;
    ushort4 s;
    s.x = f2b(tile[tx * 4 + 0][p * 16 + ty]);
    s.y = f2b(tile[tx * 4 + 1][p * 16 + ty]);
    s.z = f2b(tile[tx * 4 + 2][p * 16 + ty]);
    s.w = f2b(tile[tx * 4 + 3][p * 16 + ty]);
    *(ushort4*)(Ol + (size_t)(ro + n) * K + k0 + tx * 4) = s;
  }
}

// ---------------- embedding + sinusoidal PE -------------------------------
__global__ void embed_pe_kernel(const int* __restrict__ idx,
                                const float* __restrict__ embed,
                                float* __restrict__ x) {
  int i = blockIdx.x;            // 0..B*T-1
  int t = i & (TSEQ - 1);
  int tok = idx[i];
  int c = threadIdx.x * 4;       // 128 threads * 4 = 512
  float4 e = *(const float4*)(embed + (size_t)tok * DMODEL + c);
  float vals[4] = {e.x, e.y, e.z, e.w};
  float o[4];
#pragma unroll
  for (int j = 0; j < 4; ++j) {
    int col = c + j;
    int jj = (col < 256) ? col : col - 256;
    float div = __expf((float)jj * -0.035977892078032f);
    float arg = (float)t * div;
    o[j] = vals[j] + ((col < 256) ? __sinf(arg) : __cosf(arg));
  }
  float4 r = {o[0], o[1], o[2], o[3]};
  *(float4*)(x + (size_t)i * DMODEL + c) = r;
}

// ---------------- LayerNorm (wave per row, 2-pass) ------------------------
template <bool OUT_BF16>
__global__ __launch_bounds__(256) void ln_kernel(
    const float* __restrict__ x, const float* __restrict__ gamma,
    const float* __restrict__ beta, void* __restrict__ out) {
  int wave = threadIdx.x >> 6, lane = threadIdx.x & 63;
  int row = (blockIdx.x << 2) + wave;
  const float* xr = x + (size_t)row * DMODEL + lane * 8;
  float4 a = *(const float4*)xr;
  float4 b = *(const float4*)(xr + 4);
  float v[8] = {a.x, a.y, a.z, a.w, b.x, b.y, b.z, b.w};
  float s = 0.f;
#pragma unroll
  for (int j = 0; j < 8; ++j) s += v[j];
#pragma unroll
  for (int off = 1; off < 64; off <<= 1) s += __shfl_xor(s, off, 64);
  float mean = s * (1.0f / 512.0f);
  float q = 0.f;
#pragma unroll
  for (int j = 0; j < 8; ++j) { float d = v[j] - mean; q += d * d; }
#pragma unroll
  for (int off = 1; off < 64; off <<= 1) q += __shfl_xor(q, off, 64);
  float rstd = rsqrtf(q * (1.0f / 512.0f) + 1e-6f);
  float4 g0 = *(const float4*)(gamma + lane * 8);
  float4 g1 = *(const float4*)(gamma + lane * 8 + 4);
  float4 p0 = *(const float4*)(beta + lane * 8);
  float4 p1 = *(const float4*)(beta + lane * 8 + 4);
  float g[8] = {g0.x, g0.y, g0.z, g0.w, g1.x, g1.y, g1.z, g1.w};
  float be[8] = {p0.x, p0.y, p0.z, p0.w, p1.x, p1.y, p1.z, p1.w};
  float r[8];
#pragma unroll
  for (int j = 0; j < 8; ++j) r[j] = (v[j] - mean) * rstd * g[j] + be[j];
  if (OUT_BF16) {
    uint4 pk;
    pk.x = (u32)f2b(r[0]) | ((u32)f2b(r[1]) << 16);
    pk.y = (u32)f2b(r[2]) | ((u32)f2b(r[3]) << 16);
    pk.z = (u32)f2b(r[4]) | ((u32)f2b(r[5]) << 16);
    pk.w = (u32)f2b(r[6]) | ((u32)f2b(r[7]) << 16);
    *(uint4*)((u16*)out + (size_t)row * DMODEL + lane * 8) = pk;
  } else {
    float4 r0 = {r[0], r[1], r[2], r[3]};
    float4 r1 = {r[4], r[5], r[6], r[7]};
    float* op = (float*)out + (size_t)row * DMODEL + lane * 8;
    *(float4*)op = r0;
    *(float4*)(op + 4) = r1;
  }
}

// ---------------- bf16 MFMA GEMM: C[M][N] = A[M][K] * Bt[N][K]^T ----------
// m97 staging (global_load_lds w=16, no padding), ds_read_b128 frags, 4x4/wave.
// FLAGS: 1=bias, 2=relu, 4=fp32 residual add, 8=bf16 out (else fp32 out)
// 16=QKV split epilogue: cols<1024 -> out (qk, stride 1024) bf16;
//    cols>=1024 -> out2 = vt[(b*8+h)*64+f][4096 tokens] bf16 (transposed V)
template <int FLAGS>
__global__ __launch_bounds__(256) void gemm_kernel(
    const u16* __restrict__ A, const u16* __restrict__ Bt,
    const float* __restrict__ bias, const float* __restrict__ resid,
    void* __restrict__ out, void* __restrict__ out2, int M, int N, int K) {
  __shared__ __align__(16) u16 a_lds[128][32];
  __shared__ __align__(16) u16 b_lds[128][32];
  int m0 = blockIdx.y * 128, n0 = blockIdx.x * 128;
  int t = threadIdx.x;
  int lr = t >> 2, lc = (t & 3) * 8;
  int wave = t >> 6, lane = t & 63;
  int wm = (wave >> 1) * 64, wn = (wave & 1) * 64;
  int fr = lane & 15, quad = lane >> 4;

  f32x4 acc[4][4];
  f32x4 zz = {0.f, 0.f, 0.f, 0.f};
#pragma unroll
  for (int i = 0; i < 4; ++i)
#pragma unroll
    for (int j = 0; j < 4; ++j) acc[i][j] = zz;

  const u16* Ag0 = A + (size_t)(m0 + lr) * K + lc;
  const u16* Ag1 = A + (size_t)(m0 + lr + 64) * K + lc;
  const u16* Bg0 = Bt + (size_t)(n0 + lr) * K + lc;
  const u16* Bg1 = Bt + (size_t)(n0 + lr + 64) * K + lc;
  u16* lA0 = &a_lds[lr][lc];
  u16* lA1 = &a_lds[lr + 64][lc];
  u16* lB0 = &b_lds[lr][lc];
  u16* lB1 = &b_lds[lr + 64][lc];

  for (int k0 = 0; k0 < K; k0 += 32) {
    __syncthreads();
    __builtin_amdgcn_global_load_lds(GPTR(Ag0 + k0), LPTR(lA0), 16, 0, 0);
    __builtin_amdgcn_global_load_lds(GPTR(Ag1 + k0), LPTR(lA1), 16, 0, 0);
    __builtin_amdgcn_global_load_lds(GPTR(Bg0 + k0), LPTR(lB0), 16, 0, 0);
    __builtin_amdgcn_global_load_lds(GPTR(Bg1 + k0), LPTR(lB1), 16, 0, 0);
    __syncthreads();
    short8 af[4], bf[4];
#pragma unroll
    for (int mi = 0; mi < 4; ++mi)
      af[mi] = *(const short8*)&a_lds[wm + mi * 16 + fr][quad * 8];
#pragma unroll
    for (int ni = 0; ni < 4; ++ni)
      bf[ni] = *(const short8*)&b_lds[wn + ni * 16 + fr][quad * 8];
#pragma unroll
    for (int mi = 0; mi < 4; ++mi)
#pragma unroll
      for (int ni = 0; ni < 4; ++ni)
        acc[mi][ni] = __builtin_amdgcn_mfma_f32_16x16x32_bf16(
            af[mi], bf[ni], acc[mi][ni], 0, 0, 0);
  }

  if (FLAGS & 16) {
#pragma unroll
    for (int mi = 0; mi < 4; ++mi)
#pragma unroll
      for (int ni = 0; ni < 4; ++ni) {
        int colg = n0 + wn + ni * 16 + fr;
        if (colg < 1024) {
#pragma unroll
          for (int r = 0; r < 4; ++r) {
            int rowg = m0 + wm + mi * 16 + quad * 4 + r;
            ((u16*)out)[(size_t)rowg * 1024 + colg] = f2b(acc[mi][ni][r]);
          }
        } else {
          int hh = (colg - 1024) >> 6, ff = colg & 63;
          int rowg0 = m0 + wm + mi * 16 + quad * 4;
          int bb = rowg0 >> 12, tok = rowg0 & 4095;
          ushort4 pk;
          pk.x = f2b(acc[mi][ni][0]);
          pk.y = f2b(acc[mi][ni][1]);
          pk.z = f2b(acc[mi][ni][2]);
          pk.w = f2b(acc[mi][ni][3]);
          *(ushort4*)((u16*)out2 +
                      ((size_t)(bb * 8 + hh) * 64 + ff) * 4096 + tok) = pk;
        }
      }
    return;
  }

#pragma unroll
  for (int mi = 0; mi < 4; ++mi)
#pragma unroll
    for (int ni = 0; ni < 4; ++ni) {
      int colg = n0 + wn + ni * 16 + fr;
      float bv = (FLAGS & 1) ? bias[colg] : 0.0f;
#pragma unroll
      for (int r = 0; r < 4; ++r) {
        int rowg = m0 + wm + mi * 16 + quad * 4 + r;
        float val = acc[mi][ni][r] + bv;
        if (FLAGS & 2) val = fmaxf(val, 0.0f);
        if (FLAGS & 4) val += resid[(size_t)rowg * N + colg];
        if (FLAGS & 8)
          ((u16*)out)[(size_t)rowg * N + colg] = f2b(val);
        else
          ((float*)out)[(size_t)rowg * N + colg] = val;
      }
    }
}

// ---------------- MFMA local block attention ------------------------------
// qk:  [B*T][1024] bf16 (q cols 0..511 by head, k cols 512..1023)
// vt:  [(b*8+h)*64+f][4096] bf16 (V transposed, written by QKV GEMM)
// o:   [B*T][512] bf16
// grid (nb, 4, B), 128 threads; wave w handles head = blockIdx.y*2 + w.
// Computes S^T = K·Q^T (A=K, B=Q) so softmax over keys is nearly lane-local,
// P round-trips through LDS into A-layout, PV uses vt rows as B-frags.
__global__ __launch_bounds__(128) void attn_mfma_kernel(
    const u16* __restrict__ qk, const u16* __restrict__ vt,
    const int* __restrict__ tokens, u16* __restrict__ o, int sh) {
  __shared__ __align__(16) u16 ps[2][64][72]; // P[q][key], pad 72 (2-way free)
  __shared__ float kmask[64];
  int n = blockIdx.x, hg = blockIdx.y, b = blockIdx.z;
  int tid = threadIdx.x;
  int w = tid >> 6, lane = tid & 63;
  int head = hg * 2 + w;
  int fr = lane & 15, quad = lane >> 4;

  if (tid < 64) {
    int pp = n * 64 + tid - sh;
    kmask[tid] =
        (pp >= 0 && pp < TSEQ && tokens[(size_t)b * TSEQ + pp] > 0) ? 1.f : 0.f;
  }
  __syncthreads();

  const u16* qkb = qk + (size_t)b * TSEQ * 1024;

  // ---- S^T = K·Q^T : st[mi][ni][r] = S[q=ni*16+fr][key=mi*16+quad*4+r]
  f32x4 st[4][4];
  f32x4 zz = {0.f, 0.f, 0.f, 0.f};
#pragma unroll
  for (int i = 0; i < 4; ++i)
#pragma unroll
    for (int j = 0; j < 4; ++j) st[i][j] = zz;
#pragma unroll
  for (int kk = 0; kk < 2; ++kk) {
    short8 ka[4], qb[4];
#pragma unroll
    for (int mi = 0; mi < 4; ++mi) {
      int p = n * 64 + mi * 16 + fr - sh;
      ka[mi] = ld8g(qkb + (ptrdiff_t)p * 1024 + 512 + head * 64 + kk * 32 + quad * 8,
                    p >= 0 && p < TSEQ);
    }
#pragma unroll
    for (int ni = 0; ni < 4; ++ni) {
      int p = n * 64 + ni * 16 + fr - sh;
      qb[ni] = ld8g(qkb + (ptrdiff_t)p * 1024 + head * 64 + kk * 32 + quad * 8,
                    p >= 0 && p < TSEQ);
    }
#pragma unroll
    for (int mi = 0; mi < 4; ++mi)
#pragma unroll
      for (int ni = 0; ni < 4; ++ni)
        st[mi][ni] = __builtin_amdgcn_mfma_f32_16x16x32_bf16(
            ka[mi], qb[ni], st[mi][ni], 0, 0, 0);
  }

  // ---- mask + softmax over keys (per q column = fixed fr, ni)
  float kmv[4][4];
#pragma unroll
  for (int mi = 0; mi < 4; ++mi)
#pragma unroll
    for (int r = 0; r < 4; ++r) kmv[mi][r] = kmask[mi * 16 + quad * 4 + r];
#pragma unroll
  for (int ni = 0; ni < 4; ++ni) {
    float mx = -3.0e38f;
#pragma unroll
    for (int mi = 0; mi < 4; ++mi)
#pragma unroll
      for (int r = 0; r < 4; ++r) {
        float s = (kmv[mi][r] > 0.f) ? st[mi][ni][r] * 0.125f : -1.0e9f;
        st[mi][ni][r] = s;
        mx = fmaxf(mx, s);
      }
    mx = fmaxf(mx, __shfl_xor(mx, 16, 64));
    mx = fmaxf(mx, __shfl_xor(mx, 32, 64));
    float sm = 0.f;
#pragma unroll
    for (int mi = 0; mi < 4; ++mi)
#pragma unroll
      for (int r = 0; r < 4; ++r) {
        float e = __expf(st[mi][ni][r] - mx);
        st[mi][ni][r] = e;
        sm += e;
      }
    sm += __shfl_xor(sm, 16, 64);
    sm += __shfl_xor(sm, 32, 64);
    float inv = 1.0f / sm;
#pragma unroll
    for (int mi = 0; mi < 4; ++mi)
#pragma unroll
      for (int r = 0; r < 4; ++r) st[mi][ni][r] *= inv;
  }

  // ---- write P[q][key] to LDS (A-layout source)
#pragma unroll
  for (int mi = 0; mi < 4; ++mi)
#pragma unroll
    for (int ni = 0; ni < 4; ++ni) {
      uint2 pk;
      pk.x = (u32)f2b(st[mi][ni][0]) | ((u32)f2b(st[mi][ni][1]) << 16);
      pk.y = (u32)f2b(st[mi][ni][2]) | ((u32)f2b(st[mi][ni][3]) << 16);
      *(uint2*)&ps[w][ni * 16 + fr][mi * 16 + quad * 4] = pk;
    }
  __syncthreads(); // cross-lane LDS visibility (cheap: 2 waves)

  // ---- O = P·V : A = P[q][key] from LDS, B = vt[f][key] from global
  f32x4 oc[4][4];
#pragma unroll
  for (int i = 0; i < 4; ++i)
#pragma unroll
    for (int j = 0; j < 4; ++j) oc[i][j] = zz;
  const u16* vtb = vt + (size_t)(b * 8 + head) * 64 * 4096;
#pragma unroll
  for (int kk = 0; kk < 2; ++kk) {
    short8 pa[4], vb[4];
#pragma unroll
    for (int mi = 0; mi < 4; ++mi)
      pa[mi] = *(const short8*)&ps[w][mi * 16 + fr][kk * 32 + quad * 8];
    int key0 = n * 64 - sh + kk * 32 + quad * 8;
    bool kok = (key0 >= 0) && (key0 < TSEQ);
#pragma unroll
    for (int ni = 0; ni < 4; ++ni)
      vb[ni] = ld8g(vtb + (size_t)(ni * 16 + fr) * 4096 + key0, kok);
#pragma unroll
    for (int mi = 0; mi < 4; ++mi)
#pragma unroll
      for (int ni = 0; ni < 4; ++ni)
        oc[mi][ni] = __builtin_amdgcn_mfma_f32_16x16x32_bf16(
            pa[mi], vb[ni], oc[mi][ni], 0, 0, 0);
  }

  // ---- store O[q][f] -> obuf bf16
#pragma unroll
  for (int mi = 0; mi < 4; ++mi)
#pragma unroll
    for (int ni = 0; ni < 4; ++ni)
#pragma unroll
      for (int r = 0; r < 4; ++r) {
        int q = mi * 16 + quad * 4 + r;
        int p = n * 64 + q - sh;
        if (p >= 0 && p < TSEQ)
          o[((size_t)(b * TSEQ + p)) * DMODEL + head * 64 + ni * 16 + fr] =
              f2b(oc[mi][ni][r]);
      }
}

// ---------------------------------------------------------------------------
extern "C" void kernel_launch(void* const* d_in, const int* in_sizes, int n_in,
                              void* d_out, int out_size, void* d_ws, size_t ws_size,
                              hipStream_t stream) {
  (void)in_sizes; (void)n_in; (void)out_size; (void)ws_size;
  const int*   tokens = (const int*)d_in[0];
  const float* embed  = (const float*)d_in[1];
  const float* wq = (const float*)d_in[2];
  const float* wk = (const float*)d_in[3];
  const float* wv = (const float*)d_in[4];
  const float* wo = (const float*)d_in[5];
  const float* ln1_s = (const float*)d_in[6];
  const float* ln1_b = (const float*)d_in[7];
  const float* ln2_s = (const float*)d_in[8];
  const float* ln2_b = (const float*)d_in[9];
  const float* w1 = (const float*)d_in[10];
  const float* b1 = (const float*)d_in[11];
  const float* w2 = (const float*)d_in[12];
  const float* b2 = (const float*)d_in[13];
  const float* lnf_s = (const float*)d_in[14];
  const float* lnf_b = (const float*)d_in[15];

  char* ws = (char*)d_ws;
  const size_t MB = 1024ull * 1024ull;
  float* x     = (float*)(ws + 0);        // 32 MB fp32 residual
  u16* h       = (u16*)(ws + 32 * MB);    // 16 MB bf16 LN out
  u16* qk      = (u16*)(ws + 48 * MB);    // 33.5 MB bf16 [B*T][1024]
  u16* vt      = (u16*)(ws + 82 * MB);    // 16.8 MB bf16 V^T
  u16* obuf    = (u16*)(ws + 99 * MB);    // 16.8 MB bf16
  u16* hidden  = (u16*)(ws + 48 * MB);    // 64 MB (aliases qk/vt/obuf, disjoint in time)
  u16* wqkv_bt = (u16*)(ws + 116 * MB);   // 9 MB
  u16* wo_bt   = (u16*)(ws + 126 * MB);   // 3.1 MB
  u16* w1_bt   = (u16*)(ws + 130 * MB);   // 12.6 MB
  u16* w2_bt   = (u16*)(ws + 143 * MB);   // 12.6 MB (total ~156 MB)

  transpose_convert_all<<<dim3(768, 6), 256, 0, stream>>>(
      wq, wk, wv, wo, w1, w2, wqkv_bt, wo_bt, w1_bt, w2_bt);

  embed_pe_kernel<<<16384, 128, 0, stream>>>(tokens, embed, x);

  for (int l = 0; l < NLAYER; ++l) {
    int sh = (l & 1) ? 32 : 0;
    int nb = (l & 1) ? 65 : 64;
    ln_kernel<true><<<4096, 256, 0, stream>>>(x, ln1_s + l * 512, ln1_b + l * 512, h);
    gemm_kernel<16><<<dim3(12, 128), 256, 0, stream>>>(
        h, wqkv_bt + (size_t)l * 1536 * 512, nullptr, nullptr, qk, vt,
        16384, 1536, 512);
    attn_mfma_kernel<<<dim3(nb, 4, 4), 128, 0, stream>>>(qk, vt, tokens, obuf, sh);
    gemm_kernel<4><<<dim3(4, 128), 256, 0, stream>>>(
        obuf, wo_bt + (size_t)l * 512 * 512, nullptr, x, x, nullptr,
        16384, 512, 512);
    ln_kernel<true><<<4096, 256, 0, stream>>>(x, ln2_s + l * 512, ln2_b + l * 512, h);
    gemm_kernel<1 | 2 | 8><<<dim3(16, 128), 256, 0, stream>>>(
        h, w1_bt + (size_t)l * 2048 * 512, b1 + l * 2048, nullptr, hidden, nullptr,
        16384, 2048, 512);
    gemm_kernel<1 | 4><<<dim3(4, 128), 256, 0, stream>>>(
        hidden, w2_bt + (size_t)l * 512 * 2048, b2 + l * 512, x, x, nullptr,
        16384, 512, 2048);
  }
  ln_kernel<false><<<4096, 256, 0, stream>>>(x, lnf_s, lnf_b, d_out);
}

// Round 4
// 1567.050 us; speedup vs baseline: 1.1913x; 1.0390x over previous
//
#include <hip/hip_runtime.h>

typedef unsigned short u16;
typedef unsigned int   u32;
typedef __attribute__((ext_vector_type(8))) short short8; // 8 x bf16 (4 VGPRs)
typedef __attribute__((ext_vector_type(4))) float f32x4;  // mfma accumulator

#define TSEQ   4096
#define DMODEL 512
#define NHEAD  8
#define HDIM   64
#define NLAYER 6
#define MLPD   2048

#define GPTR(p) (const __attribute__((address_space(1))) void*)(p)
#define LPTR(p) (__attribute__((address_space(3))) void*)(p)

__device__ __forceinline__ u16 f2b(float f) {
  u32 u = __float_as_uint(f);
  u32 r = (u + 0x7fffu + ((u >> 16) & 1u)) >> 16; // RNE
  return (u16)r;
}
__device__ __forceinline__ float b2f(u16 h) { return __uint_as_float(((u32)h) << 16); }

__device__ __forceinline__ short8 ld8g(const u16* p, bool ok) {
  if (ok) return *(const short8*)p;
  short8 z = {0, 0, 0, 0, 0, 0, 0, 0};
  return z;
}

// ---------------- merged weight transpose + fp32->bf16 convert ------------
__global__ __launch_bounds__(256) void transpose_convert_all(
    const float* __restrict__ wq, const float* __restrict__ wk,
    const float* __restrict__ wv, const float* __restrict__ wo,
    const float* __restrict__ w1, const float* __restrict__ w2,
    u16* __restrict__ wqkv_bt, u16* __restrict__ wo_bt,
    u16* __restrict__ w1_bt, u16* __restrict__ w2_bt) {
  __shared__ float tile[64][65];
  int bx = blockIdx.x, l = blockIdx.y;
  const float* W; u16* out; int K, N, Ntot, ro, kb, nb2;
  if (bx < 256) {
    int which = bx >> 6, local = bx & 63;
    K = 512; N = 512; kb = local & 7; nb2 = local >> 3;
    if (which == 0)      { W = wq; out = wqkv_bt; Ntot = 1536; ro = 0; }
    else if (which == 1) { W = wk; out = wqkv_bt; Ntot = 1536; ro = 512; }
    else if (which == 2) { W = wv; out = wqkv_bt; Ntot = 1536; ro = 1024; }
    else                 { W = wo; out = wo_bt;   Ntot = 512;  ro = 0; }
  } else if (bx < 512) {
    int local = bx - 256;
    W = w1; out = w1_bt; K = 512; N = 2048; Ntot = 2048; ro = 0;
    kb = local & 7; nb2 = local >> 3;
  } else {
    int local = bx - 512;
    W = w2; out = w2_bt; K = 2048; N = 512; Ntot = 512; ro = 0;
    kb = local >> 3; nb2 = local & 7;
  }
  int k0 = kb * 64, n0 = nb2 * 64;
  const float* Wl = W + (size_t)l * K * N;
  u16* Ol = out + (size_t)l * Ntot * K;
  int tx = threadIdx.x & 15, ty = threadIdx.x >> 4;
#pragma unroll
  for (int p = 0; p < 4; ++p) {
    int k = k0 + p * 16 + ty;
    float4 v = *(const float4*)(Wl + (size_t)k * N + n0 + tx * 4);
    tile[p * 16 + ty][tx * 4 + 0] = v.x;
    tile[p * 16 + ty][tx * 4 + 1] = v.y;
    tile[p * 16 + ty][tx * 4 + 2] = v.z;
    tile[p * 16 + ty][tx * 4 + 3] = v.w;
  }
  __syncthreads();
#pragma unroll
  for (int p = 0; p < 4; ++p) {
    int n = n0 + p * 16 + ty;
    ushort4 s;
    s.x = f2b(tile[tx * 4 + 0][p * 16 + ty]);
    s.y = f2b(tile[tx * 4 + 1][p * 16 + ty]);
    s.z = f2b(tile[tx * 4 + 2][p * 16 + ty]);
    s.w = f2b(tile[tx * 4 + 3][p * 16 + ty]);
    *(ushort4*)(Ol + (size_t)(ro + n) * K + k0 + tx * 4) = s;
  }
}

// ---------------- embedding + sinusoidal PE -------------------------------
__global__ void embed_pe_kernel(const int* __restrict__ idx,
                                const float* __restrict__ embed,
                                float* __restrict__ x) {
  int i = blockIdx.x;
  int t = i & (TSEQ - 1);
  int tok = idx[i];
  int c = threadIdx.x * 4;
  float4 e = *(const float4*)(embed + (size_t)tok * DMODEL + c);
  float vals[4] = {e.x, e.y, e.z, e.w};
  float o[4];
#pragma unroll
  for (int j = 0; j < 4; ++j) {
    int col = c + j;
    int jj = (col < 256) ? col : col - 256;
    float div = __expf((float)jj * -0.035977892078032f);
    float arg = (float)t * div;
    o[j] = vals[j] + ((col < 256) ? __sinf(arg) : __cosf(arg));
  }
  float4 r = {o[0], o[1], o[2], o[3]};
  *(float4*)(x + (size_t)i * DMODEL + c) = r;
}

// ---------------- LayerNorm (wave per row, 2-pass) ------------------------
template <bool OUT_BF16>
__global__ __launch_bounds__(256) void ln_kernel(
    const float* __restrict__ x, const float* __restrict__ gamma,
    const float* __restrict__ beta, void* __restrict__ out) {
  int wave = threadIdx.x >> 6, lane = threadIdx.x & 63;
  int row = (blockIdx.x << 2) + wave;
  const float* xr = x + (size_t)row * DMODEL + lane * 8;
  float4 a = *(const float4*)xr;
  float4 b = *(const float4*)(xr + 4);
  float v[8] = {a.x, a.y, a.z, a.w, b.x, b.y, b.z, b.w};
  float s = 0.f;
#pragma unroll
  for (int j = 0; j < 8; ++j) s += v[j];
#pragma unroll
  for (int off = 1; off < 64; off <<= 1) s += __shfl_xor(s, off, 64);
  float mean = s * (1.0f / 512.0f);
  float q = 0.f;
#pragma unroll
  for (int j = 0; j < 8; ++j) { float d = v[j] - mean; q += d * d; }
#pragma unroll
  for (int off = 1; off < 64; off <<= 1) q += __shfl_xor(q, off, 64);
  float rstd = rsqrtf(q * (1.0f / 512.0f) + 1e-6f);
  float4 g0 = *(const float4*)(gamma + lane * 8);
  float4 g1 = *(const float4*)(gamma + lane * 8 + 4);
  float4 p0 = *(const float4*)(beta + lane * 8);
  float4 p1 = *(const float4*)(beta + lane * 8 + 4);
  float g[8] = {g0.x, g0.y, g0.z, g0.w, g1.x, g1.y, g1.z, g1.w};
  float be[8] = {p0.x, p0.y, p0.z, p0.w, p1.x, p1.y, p1.z, p1.w};
  float r[8];
#pragma unroll
  for (int j = 0; j < 8; ++j) r[j] = (v[j] - mean) * rstd * g[j] + be[j];
  if (OUT_BF16) {
    uint4 pk;
    pk.x = (u32)f2b(r[0]) | ((u32)f2b(r[1]) << 16);
    pk.y = (u32)f2b(r[2]) | ((u32)f2b(r[3]) << 16);
    pk.z = (u32)f2b(r[4]) | ((u32)f2b(r[5]) << 16);
    pk.w = (u32)f2b(r[6]) | ((u32)f2b(r[7]) << 16);
    *(uint4*)((u16*)out + (size_t)row * DMODEL + lane * 8) = pk;
  } else {
    float4 r0 = {r[0], r[1], r[2], r[3]};
    float4 r1 = {r[4], r[5], r[6], r[7]};
    float* op = (float*)out + (size_t)row * DMODEL + lane * 8;
    *(float4*)op = r0;
    *(float4*)(op + 4) = r1;
  }
}

// ---------------- bf16 MFMA GEMM: C[M][N] = A[M][K] * Bt[N][K]^T ----------
// K-loop: 3-stage rotating LDS buffers, prefetch distance 1, ONE raw
// s_barrier per iteration with manual s_waitcnt vmcnt(4) — the prefetch
// (4 newest loads) stays in flight across the barrier (AITER-style).
// 3 buffers are required for WAR safety: buffer (t+1)%3 was last read in
// iteration t-2, and every wave is past barrier t-1 when tile t+1 is issued.
// FLAGS: 1=bias, 2=relu, 4=fp32 residual add, 8=bf16 out (else fp32 out)
// 16=QKV split epilogue (qk + transposed V)
template <int FLAGS>
__global__ __launch_bounds__(256) void gemm_kernel(
    const u16* __restrict__ A, const u16* __restrict__ Bt,
    const float* __restrict__ bias, const float* __restrict__ resid,
    void* __restrict__ out, void* __restrict__ out2, int M, int N, int K) {
  __shared__ __align__(16) u16 a_lds[3][128][32]; // 3 x 8 KB
  __shared__ __align__(16) u16 b_lds[3][128][32];
  int m0 = blockIdx.y * 128, n0 = blockIdx.x * 128;
  int t = threadIdx.x;
  int lr = t >> 2, lc = (t & 3) * 8;
  int wave = t >> 6, lane = t & 63;
  int wm = (wave >> 1) * 64, wn = (wave & 1) * 64;
  int fr = lane & 15, quad = lane >> 4;

  f32x4 acc[4][4];
  f32x4 zz = {0.f, 0.f, 0.f, 0.f};
#pragma unroll
  for (int i = 0; i < 4; ++i)
#pragma unroll
    for (int j = 0; j < 4; ++j) acc[i][j] = zz;

  const u16* Ag0 = A + (size_t)(m0 + lr) * K + lc;
  const u16* Ag1 = A + (size_t)(m0 + lr + 64) * K + lc;
  const u16* Bg0 = Bt + (size_t)(n0 + lr) * K + lc;
  const u16* Bg1 = Bt + (size_t)(n0 + lr + 64) * K + lc;

  // prologue: stage tile 0 into buffer 0
  __builtin_amdgcn_global_load_lds(GPTR(Ag0), LPTR(&a_lds[0][lr][lc]), 16, 0, 0);
  __builtin_amdgcn_global_load_lds(GPTR(Ag1), LPTR(&a_lds[0][lr + 64][lc]), 16, 0, 0);
  __builtin_amdgcn_global_load_lds(GPTR(Bg0), LPTR(&b_lds[0][lr][lc]), 16, 0, 0);
  __builtin_amdgcn_global_load_lds(GPTR(Bg1), LPTR(&b_lds[0][lr + 64][lc]), 16, 0, 0);

  int T = K >> 5;
  int buf = 0;
  for (int tt = 0; tt < T; ++tt) {
    int nb = buf + 1 == 3 ? 0 : buf + 1;
    if (tt + 1 < T) {
      int off = (tt + 1) << 5;
      __builtin_amdgcn_global_load_lds(GPTR(Ag0 + off), LPTR(&a_lds[nb][lr][lc]), 16, 0, 0);
      __builtin_amdgcn_global_load_lds(GPTR(Ag1 + off), LPTR(&a_lds[nb][lr + 64][lc]), 16, 0, 0);
      __builtin_amdgcn_global_load_lds(GPTR(Bg0 + off), LPTR(&b_lds[nb][lr][lc]), 16, 0, 0);
      __builtin_amdgcn_global_load_lds(GPTR(Bg1 + off), LPTR(&b_lds[nb][lr + 64][lc]), 16, 0, 0);
      // tile tt ready when only the 4 prefetch loads remain outstanding
      asm volatile("s_waitcnt vmcnt(4)\n\ts_barrier" ::: "memory");
    } else {
      asm volatile("s_waitcnt vmcnt(0)\n\ts_barrier" ::: "memory");
    }
    short8 af[4], bf[4];
#pragma unroll
    for (int mi = 0; mi < 4; ++mi)
      af[mi] = *(const short8*)&a_lds[buf][wm + mi * 16 + fr][quad * 8];
#pragma unroll
    for (int ni = 0; ni < 4; ++ni)
      bf[ni] = *(const short8*)&b_lds[buf][wn + ni * 16 + fr][quad * 8];
#pragma unroll
    for (int mi = 0; mi < 4; ++mi)
#pragma unroll
      for (int ni = 0; ni < 4; ++ni)
        acc[mi][ni] = __builtin_amdgcn_mfma_f32_16x16x32_bf16(
            af[mi], bf[ni], acc[mi][ni], 0, 0, 0);
    buf = nb;
  }

  if (FLAGS & 16) {
#pragma unroll
    for (int mi = 0; mi < 4; ++mi)
#pragma unroll
      for (int ni = 0; ni < 4; ++ni) {
        int colg = n0 + wn + ni * 16 + fr;
        if (colg < 1024) {
#pragma unroll
          for (int r = 0; r < 4; ++r) {
            int rowg = m0 + wm + mi * 16 + quad * 4 + r;
            ((u16*)out)[(size_t)rowg * 1024 + colg] = f2b(acc[mi][ni][r]);
          }
        } else {
          int hh = (colg - 1024) >> 6, ff = colg & 63;
          int rowg0 = m0 + wm + mi * 16 + quad * 4;
          int bb = rowg0 >> 12, tok = rowg0 & 4095;
          ushort4 pk;
          pk.x = f2b(acc[mi][ni][0]);
          pk.y = f2b(acc[mi][ni][1]);
          pk.z = f2b(acc[mi][ni][2]);
          pk.w = f2b(acc[mi][ni][3]);
          *(ushort4*)((u16*)out2 +
                      ((size_t)(bb * 8 + hh) * 64 + ff) * 4096 + tok) = pk;
        }
      }
    return;
  }

#pragma unroll
  for (int mi = 0; mi < 4; ++mi)
#pragma unroll
    for (int ni = 0; ni < 4; ++ni) {
      int colg = n0 + wn + ni * 16 + fr;
      float bv = (FLAGS & 1) ? bias[colg] : 0.0f;
#pragma unroll
      for (int r = 0; r < 4; ++r) {
        int rowg = m0 + wm + mi * 16 + quad * 4 + r;
        float val = acc[mi][ni][r] + bv;
        if (FLAGS & 2) val = fmaxf(val, 0.0f);
        if (FLAGS & 4) val += resid[(size_t)rowg * N + colg];
        if (FLAGS & 8)
          ((u16*)out)[(size_t)rowg * N + colg] = f2b(val);
        else
          ((float*)out)[(size_t)rowg * N + colg] = val;
      }
    }
}

// ---------------- MFMA local block attention ------------------------------
__global__ __launch_bounds__(128) void attn_mfma_kernel(
    const u16* __restrict__ qk, const u16* __restrict__ vt,
    const int* __restrict__ tokens, u16* __restrict__ o, int sh) {
  __shared__ __align__(16) u16 ps[2][64][72];
  __shared__ float kmask[64];
  int n = blockIdx.x, hg = blockIdx.y, b = blockIdx.z;
  int tid = threadIdx.x;
  int w = tid >> 6, lane = tid & 63;
  int head = hg * 2 + w;
  int fr = lane & 15, quad = lane >> 4;

  if (tid < 64) {
    int pp = n * 64 + tid - sh;
    kmask[tid] =
        (pp >= 0 && pp < TSEQ && tokens[(size_t)b * TSEQ + pp] > 0) ? 1.f : 0.f;
  }
  __syncthreads();

  const u16* qkb = qk + (size_t)b * TSEQ * 1024;

  f32x4 st[4][4];
  f32x4 zz = {0.f, 0.f, 0.f, 0.f};
#pragma unroll
  for (int i = 0; i < 4; ++i)
#pragma unroll
    for (int j = 0; j < 4; ++j) st[i][j] = zz;
#pragma unroll
  for (int kk = 0; kk < 2; ++kk) {
    short8 ka[4], qb[4];
#pragma unroll
    for (int mi = 0; mi < 4; ++mi) {
      int p = n * 64 + mi * 16 + fr - sh;
      ka[mi] = ld8g(qkb + (ptrdiff_t)p * 1024 + 512 + head * 64 + kk * 32 + quad * 8,
                    p >= 0 && p < TSEQ);
    }
#pragma unroll
    for (int ni = 0; ni < 4; ++ni) {
      int p = n * 64 + ni * 16 + fr - sh;
      qb[ni] = ld8g(qkb + (ptrdiff_t)p * 1024 + head * 64 + kk * 32 + quad * 8,
                    p >= 0 && p < TSEQ);
    }
#pragma unroll
    for (int mi = 0; mi < 4; ++mi)
#pragma unroll
      for (int ni = 0; ni < 4; ++ni)
        st[mi][ni] = __builtin_amdgcn_mfma_f32_16x16x32_bf16(
            ka[mi], qb[ni], st[mi][ni], 0, 0, 0);
  }

  float kmv[4][4];
#pragma unroll
  for (int mi = 0; mi < 4; ++mi)
#pragma unroll
    for (int r = 0; r < 4; ++r) kmv[mi][r] = kmask[mi * 16 + quad * 4 + r];
#pragma unroll
  for (int ni = 0; ni < 4; ++ni) {
    float mx = -3.0e38f;
#pragma unroll
    for (int mi = 0; mi < 4; ++mi)
#pragma unroll
      for (int r = 0; r < 4; ++r) {
        float s = (kmv[mi][r] > 0.f) ? st[mi][ni][r] * 0.125f : -1.0e9f;
        st[mi][ni][r] = s;
        mx = fmaxf(mx, s);
      }
    mx = fmaxf(mx, __shfl_xor(mx, 16, 64));
    mx = fmaxf(mx, __shfl_xor(mx, 32, 64));
    float sm = 0.f;
#pragma unroll
    for (int mi = 0; mi < 4; ++mi)
#pragma unroll
      for (int r = 0; r < 4; ++r) {
        float e = __expf(st[mi][ni][r] - mx);
        st[mi][ni][r] = e;
        sm += e;
      }
    sm += __shfl_xor(sm, 16, 64);
    sm += __shfl_xor(sm, 32, 64);
    float inv = 1.0f / sm;
#pragma unroll
    for (int mi = 0; mi < 4; ++mi)
#pragma unroll
      for (int r = 0; r < 4; ++r) st[mi][ni][r] *= inv;
  }

#pragma unroll
  for (int mi = 0; mi < 4; ++mi)
#pragma unroll
    for (int ni = 0; ni < 4; ++ni) {
      uint2 pk;
      pk.x = (u32)f2b(st[mi][ni][0]) | ((u32)f2b(st[mi][ni][1]) << 16);
      pk.y = (u32)f2b(st[mi][ni][2]) | ((u32)f2b(st[mi][ni][3]) << 16);
      *(uint2*)&ps[w][ni * 16 + fr][mi * 16 + quad * 4] = pk;
    }
  __syncthreads();

  f32x4 oc[4][4];
#pragma unroll
  for (int i = 0; i < 4; ++i)
#pragma unroll
    for (int j = 0; j < 4; ++j) oc[i][j] = zz;
  const u16* vtb = vt + (size_t)(b * 8 + head) * 64 * 4096;
#pragma unroll
  for (int kk = 0; kk < 2; ++kk) {
    short8 pa[4], vb[4];
#pragma unroll
    for (int mi = 0; mi < 4; ++mi)
      pa[mi] = *(const short8*)&ps[w][mi * 16 + fr][kk * 32 + quad * 8];
    int key0 = n * 64 - sh + kk * 32 + quad * 8;
    bool kok = (key0 >= 0) && (key0 < TSEQ);
#pragma unroll
    for (int ni = 0; ni < 4; ++ni)
      vb[ni] = ld8g(vtb + (size_t)(ni * 16 + fr) * 4096 + key0, kok);
#pragma unroll
    for (int mi = 0; mi < 4; ++mi)
#pragma unroll
      for (int ni = 0; ni < 4; ++ni)
        oc[mi][ni] = __builtin_amdgcn_mfma_f32_16x16x32_bf16(
            pa[mi], vb[ni], oc[mi][ni], 0, 0, 0);
  }

#pragma unroll
  for (int mi = 0; mi < 4; ++mi)
#pragma unroll
    for (int ni = 0; ni < 4; ++ni)
#pragma unroll
      for (int r = 0; r < 4; ++r) {
        int q = mi * 16 + quad * 4 + r;
        int p = n * 64 + q - sh;
        if (p >= 0 && p < TSEQ)
          o[((size_t)(b * TSEQ + p)) * DMODEL + head * 64 + ni * 16 + fr] =
              f2b(oc[mi][ni][r]);
      }
}

// ---------------------------------------------------------------------------
extern "C" void kernel_launch(void* const* d_in, const int* in_sizes, int n_in,
                              void* d_out, int out_size, void* d_ws, size_t ws_size,
                              hipStream_t stream) {
  (void)in_sizes; (void)n_in; (void)out_size; (void)ws_size;
  const int*   tokens = (const int*)d_in[0];
  const float* embed  = (const float*)d_in[1];
  const float* wq = (const float*)d_in[2];
  const float* wk = (const float*)d_in[3];
  const float* wv = (const float*)d_in[4];
  const float* wo = (const float*)d_in[5];
  const float* ln1_s = (const float*)d_in[6];
  const float* ln1_b = (const float*)d_in[7];
  const float* ln2_s = (const float*)d_in[8];
  const float* ln2_b = (const float*)d_in[9];
  const float* w1 = (const float*)d_in[10];
  const float* b1 = (const float*)d_in[11];
  const float* w2 = (const float*)d_in[12];
  const float* b2 = (const float*)d_in[13];
  const float* lnf_s = (const float*)d_in[14];
  const float* lnf_b = (const float*)d_in[15];

  char* ws = (char*)d_ws;
  const size_t MB = 1024ull * 1024ull;
  float* x     = (float*)(ws + 0);        // 32 MB fp32 residual
  u16* h       = (u16*)(ws + 32 * MB);    // 16 MB bf16 LN out
  u16* qk      = (u16*)(ws + 48 * MB);    // 33.5 MB bf16 [B*T][1024]
  u16* vt      = (u16*)(ws + 82 * MB);    // 16.8 MB bf16 V^T
  u16* obuf    = (u16*)(ws + 99 * MB);    // 16.8 MB bf16
  u16* hidden  = (u16*)(ws + 48 * MB);    // 64 MB (aliases qk/vt/obuf, disjoint in time)
  u16* wqkv_bt = (u16*)(ws + 116 * MB);   // 9 MB
  u16* wo_bt   = (u16*)(ws + 126 * MB);   // 3.1 MB
  u16* w1_bt   = (u16*)(ws + 130 * MB);   // 12.6 MB
  u16* w2_bt   = (u16*)(ws + 143 * MB);   // 12.6 MB (total ~156 MB)

  transpose_convert_all<<<dim3(768, 6), 256, 0, stream>>>(
      wq, wk, wv, wo, w1, w2, wqkv_bt, wo_bt, w1_bt, w2_bt);

  embed_pe_kernel<<<16384, 128, 0, stream>>>(tokens, embed, x);

  for (int l = 0; l < NLAYER; ++l) {
    int sh = (l & 1) ? 32 : 0;
    int nb = (l & 1) ? 65 : 64;
    ln_kernel<true><<<4096, 256, 0, stream>>>(x, ln1_s + l * 512, ln1_b + l * 512, h);
    gemm_kernel<16><<<dim3(12, 128), 256, 0, stream>>>(
        h, wqkv_bt + (size_t)l * 1536 * 512, nullptr, nullptr, qk, vt,
        16384, 1536, 512);
    attn_mfma_kernel<<<dim3(nb, 4, 4), 128, 0, stream>>>(qk, vt, tokens, obuf, sh);
    gemm_kernel<4><<<dim3(4, 128), 256, 0, stream>>>(
        obuf, wo_bt + (size_t)l * 512 * 512, nullptr, x, x, nullptr,
        16384, 512, 512);
    ln_kernel<true><<<4096, 256, 0, stream>>>(x, ln2_s + l * 512, ln2_b + l * 512, h);
    gemm_kernel<1 | 2 | 8><<<dim3(16, 128), 256, 0, stream>>>(
        h, w1_bt + (size_t)l * 2048 * 512, b1 + l * 2048, nullptr, hidden, nullptr,
        16384, 2048, 512);
    gemm_kernel<1 | 4><<<dim3(4, 128), 256, 0, stream>>>(
        hidden, w2_bt + (size_t)l * 512 * 2048, b2 + l * 512, x, x, nullptr,
        16384, 512, 2048);
  }
  ln_kernel<false><<<4096, 256, 0, stream>>>(x, lnf_s, lnf_b, d_out);
}